// Round 1
// baseline (228.554 us; speedup 1.0000x reference)
//
#include <hip/hip_runtime.h>
#include <stdint.h>

#define BATCH     10000
#define NUM_TREES 1000
#define NUM_NODES 511
#define NFEAT     256
#define DEPTH     8

#define BT 64              // batch rows per block tile
#define TT 64              // trees per block tile
#define TPR 16             // trees staged per round (= 2 per wave)
#define NROUNDS (TT / TPR) // 4
#define NTHREADS 512
#define NWAVES 8

// LDS layout
#define XS_BYTES   (BT * NFEAT * 4)         // 65536
#define NODES_PAD  512
#define NS_BYTES   (TPR * NODES_PAD * 8)    // 65536
#define OUT_LD     (TT + 1)                 // pad to kill bank conflicts
#define OS_BYTES   (BT * OUT_LD * 4)        // 16640
#define SH_BYTES   (XS_BYTES + NS_BYTES + OS_BYTES)  // 147712

// Pack one node into 8 bytes: {f32 threshold, feat[0:8) | left[8:20) | right[20:32)}
__global__ void prepack_kernel(const float* __restrict__ thr,
                               const int* __restrict__ feats,
                               const int* __restrict__ lefts,
                               const int* __restrict__ rights,
                               uint2* __restrict__ packed, int n) {
  int i = blockIdx.x * blockDim.x + threadIdx.x;
  if (i < n) {
    uint32_t meta = (uint32_t)feats[i] | ((uint32_t)lefts[i] << 8) |
                    ((uint32_t)rights[i] << 20);
    packed[i] = make_uint2(__float_as_uint(thr[i]), meta);
  }
}

template <bool PACKED>
__global__ __launch_bounds__(NTHREADS, 1)
void traverse_kernel(const float* __restrict__ x,
                     const uint2* __restrict__ packed,
                     const float* __restrict__ thrg,
                     const int* __restrict__ featg,
                     const int* __restrict__ leftg,
                     const int* __restrict__ rightg,
                     const float* __restrict__ values,
                     float* __restrict__ out) {
  extern __shared__ unsigned char smem[];
  float* x_s    = (float*)smem;                        // [BT][NFEAT]
  uint2* nodes_s = (uint2*)(smem + XS_BYTES);          // [TPR][NODES_PAD]
  float* out_s  = (float*)(smem + XS_BYTES + NS_BYTES);// [BT][OUT_LD]

  const int tid  = threadIdx.x;
  const int wid  = tid >> 6;
  const int lane = tid & 63;
  const int b0   = blockIdx.y * BT;
  const int t0   = blockIdx.x * TT;

  // ---- stage x tile (BT rows x 256 f32 = 64 KB), coalesced float4 ----
  {
    const float4* xg = (const float4*)x;
    const float4 z = make_float4(0.f, 0.f, 0.f, 0.f);
    #pragma unroll
    for (int i = tid; i < BT * (NFEAT / 4); i += NTHREADS) {
      int row = i >> 6;                 // 64 float4 per row
      int gb  = b0 + row;
      float4 v = (gb < BATCH) ? xg[gb * (NFEAT / 4) + (i & 63)] : z;
      *(float4*)(x_s + (i << 2)) = v;   // flat float idx i*4 == row*256 + col
    }
  }

  for (int r = 0; r < NROUNDS; ++r) {
    __syncthreads();  // nodes_s safe to overwrite (and x_s visible after r=0)

    // ---- stage TPR trees' packed nodes into LDS ----
    const int tr0 = t0 + r * TPR;
    if (tid < NUM_NODES) {
      #pragma unroll
      for (int j = 0; j < TPR; ++j) {
        int gt = tr0 + j;
        uint2 v;
        if (gt < NUM_TREES) {
          if (PACKED) {
            v = packed[gt * NUM_NODES + tid];
          } else {
            int gi = gt * NUM_NODES + tid;
            uint32_t meta = (uint32_t)featg[gi] | ((uint32_t)leftg[gi] << 8) |
                            ((uint32_t)rightg[gi] << 20);
            v = make_uint2(__float_as_uint(thrg[gi]), meta);
          }
        } else {
          v = make_uint2(0u, 0u);   // safe dummy tree: stays at node 0
        }
        nodes_s[j * NODES_PAD + tid] = v;
      }
    }
    __syncthreads();

    // ---- traverse: each wave walks 2 trees (ILP=2), lane = batch row ----
    const int sA = 2 * wid, sB = sA + 1;
    const uint2* nA = nodes_s + sA * NODES_PAD;
    const uint2* nB = nodes_s + sB * NODES_PAD;
    const float* xrow = x_s + lane * NFEAT;
    int ia = 0, ib = 0;
    #pragma unroll
    for (int d = 0; d < DEPTH; ++d) {
      uint2 na = nA[ia];
      uint2 nb = nB[ib];
      float xa = xrow[na.y & 0xFF];
      float xb = xrow[nb.y & 0xFF];
      ia = (xa >= __uint_as_float(na.x)) ? (int)(na.y >> 20)
                                         : (int)((na.y >> 8) & 0xFFF);
      ib = (xb >= __uint_as_float(nb.x)) ? (int)(nb.y >> 20)
                                         : (int)((nb.y >> 8) & 0xFFF);
    }
    const int ta = tr0 + sA, tb = tr0 + sB;
    float va = (ta < NUM_TREES) ? values[ta * NUM_NODES + ia] : 0.f;
    float vb = (tb < NUM_TREES) ? values[tb * NUM_NODES + ib] : 0.f;
    out_s[lane * OUT_LD + (r * TPR + sA)] = va;
    out_s[lane * OUT_LD + (r * TPR + sB)] = vb;
  }

  __syncthreads();
  // ---- flush out tile, coalesced: one 256 B row per wave per pass ----
  {
    const int gt = t0 + lane;
    #pragma unroll
    for (int p = 0; p < BT / NWAVES; ++p) {
      int row = p * NWAVES + wid;
      int gb  = b0 + row;
      if (gb < BATCH && gt < NUM_TREES)
        out[gb * NUM_TREES + t0 + lane] = out_s[row * OUT_LD + lane];
    }
  }
}

extern "C" void kernel_launch(void* const* d_in, const int* in_sizes, int n_in,
                              void* d_out, int out_size, void* d_ws, size_t ws_size,
                              hipStream_t stream) {
  const float* x          = (const float*)d_in[0];
  const float* thresholds = (const float*)d_in[1];
  const float* values     = (const float*)d_in[2];
  const int*   lefts      = (const int*)d_in[3];
  const int*   rights     = (const int*)d_in[4];
  const int*   features   = (const int*)d_in[5];
  float* out = (float*)d_out;

  const int nflat = NUM_TREES * NUM_NODES;
  dim3 grid((NUM_TREES + TT - 1) / TT, (BATCH + BT - 1) / BT);

  const bool usePacked = ws_size >= (size_t)nflat * 8;
  if (usePacked) {
    uint2* packed = (uint2*)d_ws;
    prepack_kernel<<<(nflat + 511) / 512, 512, 0, stream>>>(
        thresholds, features, lefts, rights, packed, nflat);
    hipFuncSetAttribute(reinterpret_cast<const void*>(traverse_kernel<true>),
                        hipFuncAttributeMaxDynamicSharedMemorySize, SH_BYTES);
    traverse_kernel<true><<<grid, NTHREADS, SH_BYTES, stream>>>(
        x, packed, nullptr, nullptr, nullptr, nullptr, values, out);
  } else {
    hipFuncSetAttribute(reinterpret_cast<const void*>(traverse_kernel<false>),
                        hipFuncAttributeMaxDynamicSharedMemorySize, SH_BYTES);
    traverse_kernel<false><<<grid, NTHREADS, SH_BYTES, stream>>>(
        x, nullptr, thresholds, features, lefts, rights, values, out);
  }
}

// Round 2
// 155.581 us; speedup vs baseline: 1.4690x; 1.4690x over previous
//
#include <hip/hip_runtime.h>
#include <stdint.h>

#define BATCH     10000
#define NUM_TREES 1000
#define NUM_NODES 511
#define NFEAT     256
#define DEPTH     8

#define BT 64              // batch rows per block tile
#define TT 64              // trees per block tile
#define TPR 16             // trees staged per round (= 2 per wave)
#define NROUNDS (TT / TPR) // 4
#define NTHREADS 512
#define NWAVES 8

// LDS layout
#define XS_BYTES   (NFEAT * 64 * 4)            // 65536; transposed+swizzled [feat][64]
#define NS_UINT2   (TPR * NUM_NODES)           // 8176 (stride 511, no pad)
#define NS_BYTES   (NS_UINT2 * 8)              // 65408
#define OUT_LD     (TT + 1)
#define OS_BYTES   (BT * OUT_LD * 4)           // 16640
#define SH_BYTES   (XS_BYTES + NS_BYTES + OS_BYTES)  // 147584

#define PREF       ((NS_UINT2 + NTHREADS - 1) / NTHREADS)  // 16
#define FLAT_NODES (NUM_TREES * NUM_NODES)     // 511000

// Pack one node into 8 bytes: {f32 threshold, feat[0:8) | left[8:20) | right[20:32)}
__global__ void prepack_kernel(const float* __restrict__ thr,
                               const int* __restrict__ feats,
                               const int* __restrict__ lefts,
                               const int* __restrict__ rights,
                               uint2* __restrict__ packed, int n) {
  int i = blockIdx.x * blockDim.x + threadIdx.x;
  if (i < n) {
    uint32_t meta = (uint32_t)feats[i] | ((uint32_t)lefts[i] << 8) |
                    ((uint32_t)rights[i] << 20);
    packed[i] = make_uint2(__float_as_uint(thr[i]), meta);
  }
}

template <bool PACKED>
__global__ __launch_bounds__(NTHREADS, 1)
void traverse_kernel(const float* __restrict__ x,
                     const uint2* __restrict__ packed,
                     const float* __restrict__ thrg,
                     const int* __restrict__ featg,
                     const int* __restrict__ leftg,
                     const int* __restrict__ rightg,
                     const float* __restrict__ values,
                     float* __restrict__ out) {
  extern __shared__ unsigned char smem[];
  float* x_s     = (float*)smem;                         // [256][64] swizzled
  uint2* nodes_s = (uint2*)(smem + XS_BYTES);            // [TPR][511] flat
  float* out_s   = (float*)(smem + XS_BYTES + NS_BYTES); // [BT][OUT_LD]

  const int tid  = threadIdx.x;
  const int wid  = tid >> 6;
  const int lane = tid & 63;
  const int b0   = blockIdx.y * BT;
  const int t0   = blockIdx.x * TT;

  uint2 pf[PREF];

  auto load_round = [&](int rr) {
    const int gbase = (t0 + rr * TPR) * NUM_NODES;
    #pragma unroll
    for (int k = 0; k < PREF; ++k) {
      int fi = tid + k * NTHREADS;
      uint2 v = make_uint2(0u, 0u);     // dummy tree: stays at node 0
      if (fi < NS_UINT2) {
        int gi = gbase + fi;
        if (gi < FLAT_NODES) {
          if (PACKED) {
            v = packed[gi];
          } else {
            uint32_t meta = (uint32_t)featg[gi] | ((uint32_t)leftg[gi] << 8) |
                            ((uint32_t)rightg[gi] << 20);
            v = make_uint2(__float_as_uint(thrg[gi]), meta);
          }
        }
      }
      pf[k] = v;
    }
  };
  auto write_nodes = [&]() {
    #pragma unroll
    for (int k = 0; k < PREF; ++k) {
      int fi = tid + k * NTHREADS;
      if (fi < NS_UINT2) nodes_s[fi] = pf[k];
    }
  };

  // Issue round-0 node loads first; their latency overlaps x staging.
  load_round(0);

  // ---- stage x transposed + swizzled: bank = (row ^ ((feat>>2)&31)) & 31 ----
  {
    const float4* xg = (const float4*)x;
    #pragma unroll
    for (int p = 0; p < (BT * (NFEAT / 4)) / NTHREADS; ++p) {
      int i   = tid + p * NTHREADS;
      int row = i >> 6, c = i & 63;     // row const per wave, c = lane
      int gb  = b0 + row;
      float4 v = make_float4(0.f, 0.f, 0.f, 0.f);
      if (gb < BATCH) v = xg[gb * (NFEAT / 4) + c];
      int o = (c << 8) + (row ^ (c & 31));   // feat=4c+k at o + 64*k
      x_s[o]       = v.x;
      x_s[o + 64]  = v.y;
      x_s[o + 128] = v.z;
      x_s[o + 192] = v.w;
    }
  }
  write_nodes();
  __syncthreads();

  for (int r = 0; r < NROUNDS; ++r) {
    // Prefetch next round's nodes into registers; latency hides under traversal.
    if (r + 1 < NROUNDS) load_round(r + 1);

    // ---- traverse: each wave walks 2 trees (ILP=2), lane = batch row ----
    const int sA = 2 * wid, sB = sA + 1;
    const uint2* nA = nodes_s + sA * NUM_NODES;
    const uint2* nB = nodes_s + sB * NUM_NODES;
    int ia = 0, ib = 0;
    #pragma unroll
    for (int d = 0; d < DEPTH; ++d) {
      uint2 na = nA[ia];
      uint2 nb = nB[ib];
      int fa = na.y & 0xFF, fb = nb.y & 0xFF;
      float xa = x_s[(fa << 6) + (lane ^ ((fa >> 2) & 31))];
      float xb = x_s[(fb << 6) + (lane ^ ((fb >> 2) & 31))];
      ia = (xa >= __uint_as_float(na.x)) ? (int)(na.y >> 20)
                                         : (int)((na.y >> 8) & 0xFFF);
      ib = (xb >= __uint_as_float(nb.x)) ? (int)(nb.y >> 20)
                                         : (int)((nb.y >> 8) & 0xFFF);
    }
    const int tr0 = t0 + r * TPR;
    const int ta = tr0 + sA, tb = tr0 + sB;
    float va = (ta < NUM_TREES) ? values[ta * NUM_NODES + ia] : 0.f;
    float vb = (tb < NUM_TREES) ? values[tb * NUM_NODES + ib] : 0.f;
    out_s[lane * OUT_LD + r * TPR + sA] = va;
    out_s[lane * OUT_LD + r * TPR + sB] = vb;

    __syncthreads();                 // traversal reads of nodes_s done
    if (r + 1 < NROUNDS) {
      write_nodes();                 // vmcnt wait lands here, not mid-round
      __syncthreads();
    }
  }

  // ---- flush out tile, coalesced: one 256 B row per wave per pass ----
  {
    const int gt = t0 + lane;
    #pragma unroll
    for (int p = 0; p < BT / NWAVES; ++p) {
      int row = p * NWAVES + wid;
      int gb  = b0 + row;
      if (gb < BATCH && gt < NUM_TREES)
        out[gb * NUM_TREES + gt] = out_s[row * OUT_LD + lane];
    }
  }
}

extern "C" void kernel_launch(void* const* d_in, const int* in_sizes, int n_in,
                              void* d_out, int out_size, void* d_ws, size_t ws_size,
                              hipStream_t stream) {
  const float* x          = (const float*)d_in[0];
  const float* thresholds = (const float*)d_in[1];
  const float* values     = (const float*)d_in[2];
  const int*   lefts      = (const int*)d_in[3];
  const int*   rights     = (const int*)d_in[4];
  const int*   features   = (const int*)d_in[5];
  float* out = (float*)d_out;

  const int nflat = FLAT_NODES;
  dim3 grid((NUM_TREES + TT - 1) / TT, (BATCH + BT - 1) / BT);

  const bool usePacked = ws_size >= (size_t)nflat * 8;
  if (usePacked) {
    uint2* packed = (uint2*)d_ws;
    prepack_kernel<<<(nflat + 511) / 512, 512, 0, stream>>>(
        thresholds, features, lefts, rights, packed, nflat);
    hipFuncSetAttribute(reinterpret_cast<const void*>(traverse_kernel<true>),
                        hipFuncAttributeMaxDynamicSharedMemorySize, SH_BYTES);
    traverse_kernel<true><<<grid, NTHREADS, SH_BYTES, stream>>>(
        x, packed, nullptr, nullptr, nullptr, nullptr, values, out);
  } else {
    hipFuncSetAttribute(reinterpret_cast<const void*>(traverse_kernel<false>),
                        hipFuncAttributeMaxDynamicSharedMemorySize, SH_BYTES);
    traverse_kernel<false><<<grid, NTHREADS, SH_BYTES, stream>>>(
        x, nullptr, thresholds, features, lefts, rights, values, out);
  }
}

// Round 3
// 147.128 us; speedup vs baseline: 1.5534x; 1.0575x over previous
//
#include <hip/hip_runtime.h>
#include <stdint.h>

#define BATCH     10000
#define NUM_TREES 1000
#define NUM_NODES 511
#define NFEAT     256
#define DEPTH     8

#define BT 64              // batch rows per block tile
#define TT 64              // trees per block tile
#define TPR 16             // trees staged per round (= 2 per wave)
#define NROUNDS (TT / TPR) // 4
#define NTHREADS 512
#define NWAVES 8

// LDS layout
#define XS_BYTES   (NFEAT * 64 * 4)            // 65536; transposed+swizzled [feat][64]
#define NS_UINT2   (TPR * NUM_NODES)           // 8176 (stride 511, no pad)
#define NS_BYTES   (NS_UINT2 * 8)              // 65408
#define OUT_LD     (TT + 1)
#define OS_BYTES   (BT * OUT_LD * 4)           // 16640
#define SH_BYTES   (XS_BYTES + NS_BYTES + OS_BYTES)  // 147584

#define PREF       ((NS_UINT2 + NTHREADS - 1) / NTHREADS)  // 16
#define FLAT_NODES (NUM_TREES * NUM_NODES)     // 511000

// Pack one node into 8 bytes: {f32 threshold, feat[0:8) | left[8:20) | right[20:32)}
__global__ void prepack_kernel(const float* __restrict__ thr,
                               const int* __restrict__ feats,
                               const int* __restrict__ lefts,
                               const int* __restrict__ rights,
                               uint2* __restrict__ packed, int n) {
  int i = blockIdx.x * blockDim.x + threadIdx.x;
  if (i < n) {
    uint32_t meta = (uint32_t)feats[i] | ((uint32_t)lefts[i] << 8) |
                    ((uint32_t)rights[i] << 20);
    packed[i] = make_uint2(__float_as_uint(thr[i]), meta);
  }
}

template <bool PACKED>
__global__ __launch_bounds__(NTHREADS, 1)
void traverse_kernel(const float* __restrict__ x,
                     const uint2* __restrict__ packed,
                     const float* __restrict__ thrg,
                     const int* __restrict__ featg,
                     const int* __restrict__ leftg,
                     const int* __restrict__ rightg,
                     const float* __restrict__ values,
                     float* __restrict__ out) {
  extern __shared__ unsigned char smem[];
  float* x_s     = (float*)smem;                         // [256][64] swizzled
  uint2* nodes_s = (uint2*)(smem + XS_BYTES);            // [TPR][511] flat
  float* out_s   = (float*)(smem + XS_BYTES + NS_BYTES); // [BT][OUT_LD]

  const int tid  = threadIdx.x;
  const int wid  = tid >> 6;
  const int lane = tid & 63;
  const int b0   = blockIdx.y * BT;
  const int t0   = blockIdx.x * TT;

  uint2 pf[PREF];

  auto load_round = [&](int rr) {
    const int gbase = (t0 + rr * TPR) * NUM_NODES;
    #pragma unroll
    for (int k = 0; k < PREF; ++k) {
      int fi = tid + k * NTHREADS;
      uint2 v = make_uint2(0u, 0u);     // dummy tree: stays at node 0
      if (fi < NS_UINT2) {
        int gi = gbase + fi;
        if (gi < FLAT_NODES) {
          if (PACKED) {
            v = packed[gi];
          } else {
            uint32_t meta = (uint32_t)featg[gi] | ((uint32_t)leftg[gi] << 8) |
                            ((uint32_t)rightg[gi] << 20);
            v = make_uint2(__float_as_uint(thrg[gi]), meta);
          }
        }
      }
      pf[k] = v;
    }
  };
  auto write_nodes = [&]() {
    #pragma unroll
    for (int k = 0; k < PREF; ++k) {
      int fi = tid + k * NTHREADS;
      if (fi < NS_UINT2) nodes_s[fi] = pf[k];
    }
  };

  // Issue round-0 node loads first; their latency overlaps x staging.
  load_round(0);

  // ---- stage x transposed + swizzled: bank = (row ^ ((feat>>2)&31)) & 31 ----
  {
    const float4* xg = (const float4*)x;
    #pragma unroll
    for (int p = 0; p < (BT * (NFEAT / 4)) / NTHREADS; ++p) {
      int i   = tid + p * NTHREADS;
      int row = i >> 6, c = i & 63;     // row const per wave, c = lane
      int gb  = b0 + row;
      float4 v = make_float4(0.f, 0.f, 0.f, 0.f);
      if (gb < BATCH) v = xg[gb * (NFEAT / 4) + c];
      int o = (c << 8) + (row ^ (c & 31));   // feat=4c+k at o + 64*k
      x_s[o]       = v.x;
      x_s[o + 64]  = v.y;
      x_s[o + 128] = v.z;
      x_s[o + 192] = v.w;
    }
  }
  write_nodes();
  __syncthreads();

  for (int r = 0; r < NROUNDS; ++r) {
    // Prefetch next round's nodes into registers; latency hides under traversal.
    if (r + 1 < NROUNDS) load_round(r + 1);

    // ---- traverse: each wave walks 2 trees (ILP=2), lane = batch row ----
    // Content speculation: hold node(d) CONTENTS; left/right addresses are
    // known before the x-compare, so x / node[l] / node[r] issue in parallel
    // and the compare only picks between already-loaded register pairs.
    const int sA = 2 * wid, sB = sA + 1;
    const uint2* nA = nodes_s + sA * NUM_NODES;
    const uint2* nB = nodes_s + sB * NUM_NODES;
    const int tr0 = t0 + r * TPR;
    const int gta = tr0 + sA, gtb = tr0 + sB;
    const int offA = (gta < NUM_TREES ? gta : 0) * NUM_NODES;  // clamp dummies
    const int offB = (gtb < NUM_TREES ? gtb : 0) * NUM_NODES;

    uint2 na = nA[0], nb = nB[0];
    float va = 0.f, vb = 0.f;
    #pragma unroll
    for (int d = 0; d < DEPTH; ++d) {
      int fa = na.y & 0xFF,          fb = nb.y & 0xFF;
      int la = (na.y >> 8) & 0xFFF,  lb = (nb.y >> 8) & 0xFFF;
      int ra = (int)(na.y >> 20),    rb = (int)(nb.y >> 20);
      float xa = x_s[(fa << 6) + (lane ^ ((fa >> 2) & 31))];
      float xb = x_s[(fb << 6) + (lane ^ ((fb >> 2) & 31))];
      if (d < DEPTH - 1) {
        uint2 nla = nA[la], nra = nA[ra];
        uint2 nlb = nB[lb], nrb = nB[rb];
        bool ca = (xa >= __uint_as_float(na.x));
        bool cb = (xb >= __uint_as_float(nb.x));
        na = ca ? nra : nla;
        nb = cb ? nrb : nlb;
      } else {
        // Last depth: speculate the two candidate leaf values instead
        // (global, L2-resident) — hides the end-of-round global latency.
        float vla = values[offA + la], vra = values[offA + ra];
        float vlb = values[offB + lb], vrb = values[offB + rb];
        va = (xa >= __uint_as_float(na.x)) ? vra : vla;
        vb = (xb >= __uint_as_float(nb.x)) ? vrb : vlb;
      }
    }
    out_s[lane * OUT_LD + r * TPR + sA] = va;
    out_s[lane * OUT_LD + r * TPR + sB] = vb;

    __syncthreads();                 // traversal reads of nodes_s done
    if (r + 1 < NROUNDS) {
      write_nodes();                 // vmcnt wait lands here, not mid-round
      __syncthreads();
    }
  }

  // ---- flush out tile, coalesced: one 256 B row per wave per pass ----
  {
    const int gt = t0 + lane;
    #pragma unroll
    for (int p = 0; p < BT / NWAVES; ++p) {
      int row = p * NWAVES + wid;
      int gb  = b0 + row;
      if (gb < BATCH && gt < NUM_TREES)
        out[gb * NUM_TREES + gt] = out_s[row * OUT_LD + lane];
    }
  }
}

extern "C" void kernel_launch(void* const* d_in, const int* in_sizes, int n_in,
                              void* d_out, int out_size, void* d_ws, size_t ws_size,
                              hipStream_t stream) {
  const float* x          = (const float*)d_in[0];
  const float* thresholds = (const float*)d_in[1];
  const float* values     = (const float*)d_in[2];
  const int*   lefts      = (const int*)d_in[3];
  const int*   rights     = (const int*)d_in[4];
  const int*   features   = (const int*)d_in[5];
  float* out = (float*)d_out;

  const int nflat = FLAT_NODES;
  dim3 grid((NUM_TREES + TT - 1) / TT, (BATCH + BT - 1) / BT);

  const bool usePacked = ws_size >= (size_t)nflat * 8;
  if (usePacked) {
    uint2* packed = (uint2*)d_ws;
    prepack_kernel<<<(nflat + 511) / 512, 512, 0, stream>>>(
        thresholds, features, lefts, rights, packed, nflat);
    hipFuncSetAttribute(reinterpret_cast<const void*>(traverse_kernel<true>),
                        hipFuncAttributeMaxDynamicSharedMemorySize, SH_BYTES);
    traverse_kernel<true><<<grid, NTHREADS, SH_BYTES, stream>>>(
        x, packed, nullptr, nullptr, nullptr, nullptr, values, out);
  } else {
    hipFuncSetAttribute(reinterpret_cast<const void*>(traverse_kernel<false>),
                        hipFuncAttributeMaxDynamicSharedMemorySize, SH_BYTES);
    traverse_kernel<false><<<grid, NTHREADS, SH_BYTES, stream>>>(
        x, nullptr, thresholds, features, lefts, rights, values, out);
  }
}

// Round 4
// 123.324 us; speedup vs baseline: 1.8533x; 1.1930x over previous
//
#include <hip/hip_runtime.h>
#include <stdint.h>

#define BATCH     10000
#define NUM_TREES 1000
#define NUM_NODES 511
#define NFEAT     256
#define DEPTH     8

#define BT 64              // batch rows per block tile
#define TT 64              // trees per block tile
#define TPR 16             // trees staged per round (= 1 per wave)
#define NROUNDS (TT / TPR) // 4
#define NTHREADS 1024
#define NWAVES 16

// LDS layout
#define XS_BYTES   (NFEAT * 64 * 4)            // 65536; transposed+swizzled [feat][64]
#define NS_UINT2   (TPR * NUM_NODES)           // 8176 (stride 511, no pad)
#define NS_BYTES   (NS_UINT2 * 8)              // 65408
#define OUT_LD     (TT + 1)
#define OS_BYTES   (BT * OUT_LD * 4)           // 16640
#define SH_BYTES   (XS_BYTES + NS_BYTES + OS_BYTES)  // 147584

#define PREF       ((NS_UINT2 + NTHREADS - 1) / NTHREADS)  // 8
#define FLAT_NODES (NUM_TREES * NUM_NODES)     // 511000

// Pack one node into 8 bytes: {f32 threshold, feat[0:8) | left[8:20) | right[20:32)}
__global__ void prepack_kernel(const float* __restrict__ thr,
                               const int* __restrict__ feats,
                               const int* __restrict__ lefts,
                               const int* __restrict__ rights,
                               uint2* __restrict__ packed, int n) {
  int i = blockIdx.x * blockDim.x + threadIdx.x;
  if (i < n) {
    uint32_t meta = (uint32_t)feats[i] | ((uint32_t)lefts[i] << 8) |
                    ((uint32_t)rights[i] << 20);
    packed[i] = make_uint2(__float_as_uint(thr[i]), meta);
  }
}

template <bool PACKED>
__global__ __launch_bounds__(NTHREADS, 1)
void traverse_kernel(const float* __restrict__ x,
                     const uint2* __restrict__ packed,
                     const float* __restrict__ thrg,
                     const int* __restrict__ featg,
                     const int* __restrict__ leftg,
                     const int* __restrict__ rightg,
                     const float* __restrict__ values,
                     float* __restrict__ out) {
  extern __shared__ unsigned char smem[];
  float* x_s     = (float*)smem;                         // [256][64] swizzled
  uint2* nodes_s = (uint2*)(smem + XS_BYTES);            // [TPR][511] flat
  float* out_s   = (float*)(smem + XS_BYTES + NS_BYTES); // [BT][OUT_LD]

  const int tid  = threadIdx.x;
  const int wid  = tid >> 6;
  const int lane = tid & 63;
  const int b0   = blockIdx.y * BT;
  const int t0   = blockIdx.x * TT;

  uint2 pf[PREF];

  auto load_round = [&](int rr) {
    const int gbase = (t0 + rr * TPR) * NUM_NODES;
    #pragma unroll
    for (int k = 0; k < PREF; ++k) {
      int fi = tid + k * NTHREADS;
      uint2 v = make_uint2(0u, 0u);     // dummy tree: stays at node 0
      if (fi < NS_UINT2) {
        int gi = gbase + fi;
        if (gi < FLAT_NODES) {
          if (PACKED) {
            v = packed[gi];
          } else {
            uint32_t meta = (uint32_t)featg[gi] | ((uint32_t)leftg[gi] << 8) |
                            ((uint32_t)rightg[gi] << 20);
            v = make_uint2(__float_as_uint(thrg[gi]), meta);
          }
        }
      }
      pf[k] = v;
    }
  };
  auto write_nodes = [&]() {
    #pragma unroll
    for (int k = 0; k < PREF; ++k) {
      int fi = tid + k * NTHREADS;
      if (fi < NS_UINT2) nodes_s[fi] = pf[k];
    }
  };

  // Issue round-0 node loads first; their latency overlaps x staging.
  load_round(0);

  // ---- stage x transposed + swizzled: bank = (row ^ ((feat>>2)&31)) & 31 ----
  {
    const float4* xg = (const float4*)x;
    #pragma unroll
    for (int p = 0; p < (BT * (NFEAT / 4)) / NTHREADS; ++p) {
      int i   = tid + p * NTHREADS;
      int row = i >> 6, c = i & 63;
      int gb  = b0 + row;
      float4 v = make_float4(0.f, 0.f, 0.f, 0.f);
      if (gb < BATCH) v = xg[gb * (NFEAT / 4) + c];
      int o = (c << 8) + (row ^ (c & 31));   // feat=4c+k at o + 64*k
      x_s[o]       = v.x;
      x_s[o + 64]  = v.y;
      x_s[o + 128] = v.z;
      x_s[o + 192] = v.w;
    }
  }
  write_nodes();
  __syncthreads();

  for (int r = 0; r < NROUNDS; ++r) {
    // Prefetch next round's nodes into registers; latency hides under traversal.
    if (r + 1 < NROUNDS) load_round(r + 1);

    // ---- traverse: each wave walks 1 tree, lane = batch row; TLP via 16 waves.
    // Content speculation: hold node(d) CONTENTS; left/right addresses are
    // known before the x-compare, so x / node[l] / node[r] issue in parallel
    // and the compare only picks between already-loaded register pairs.
    const uint2* nA = nodes_s + wid * NUM_NODES;
    const int tr0 = t0 + r * TPR;
    const int gta = tr0 + wid;
    const int offA = (gta < NUM_TREES ? gta : 0) * NUM_NODES;  // clamp dummies

    uint2 na = nA[0];
    float va = 0.f;
    #pragma unroll
    for (int d = 0; d < DEPTH; ++d) {
      int fa = na.y & 0xFF;
      int la = (na.y >> 8) & 0xFFF;
      int ra = (int)(na.y >> 20);
      float xa = x_s[(fa << 6) + (lane ^ ((fa >> 2) & 31))];
      if (d < DEPTH - 1) {
        uint2 nla = nA[la], nra = nA[ra];
        na = (xa >= __uint_as_float(na.x)) ? nra : nla;
      } else {
        // Last depth: speculate the two candidate leaf values instead
        // (global, L2-resident) — hides the end-of-round global latency.
        float vla = values[offA + la], vra = values[offA + ra];
        va = (xa >= __uint_as_float(na.x)) ? vra : vla;
      }
    }
    out_s[lane * OUT_LD + r * TPR + wid] = va;

    __syncthreads();                 // traversal reads of nodes_s done
    if (r + 1 < NROUNDS) {
      write_nodes();                 // vmcnt wait lands here, not mid-round
      __syncthreads();
    }
  }

  // ---- flush out tile, coalesced: one 256 B row per wave per pass ----
  {
    const int gt = t0 + lane;
    #pragma unroll
    for (int p = 0; p < BT / NWAVES; ++p) {
      int row = p * NWAVES + wid;
      int gb  = b0 + row;
      if (gb < BATCH && gt < NUM_TREES)
        out[gb * NUM_TREES + gt] = out_s[row * OUT_LD + lane];
    }
  }
}

extern "C" void kernel_launch(void* const* d_in, const int* in_sizes, int n_in,
                              void* d_out, int out_size, void* d_ws, size_t ws_size,
                              hipStream_t stream) {
  const float* x          = (const float*)d_in[0];
  const float* thresholds = (const float*)d_in[1];
  const float* values     = (const float*)d_in[2];
  const int*   lefts      = (const int*)d_in[3];
  const int*   rights     = (const int*)d_in[4];
  const int*   features   = (const int*)d_in[5];
  float* out = (float*)d_out;

  const int nflat = FLAT_NODES;
  dim3 grid((NUM_TREES + TT - 1) / TT, (BATCH + BT - 1) / BT);

  const bool usePacked = ws_size >= (size_t)nflat * 8;
  if (usePacked) {
    uint2* packed = (uint2*)d_ws;
    prepack_kernel<<<(nflat + 511) / 512, 512, 0, stream>>>(
        thresholds, features, lefts, rights, packed, nflat);
    hipFuncSetAttribute(reinterpret_cast<const void*>(traverse_kernel<true>),
                        hipFuncAttributeMaxDynamicSharedMemorySize, SH_BYTES);
    traverse_kernel<true><<<grid, NTHREADS, SH_BYTES, stream>>>(
        x, packed, nullptr, nullptr, nullptr, nullptr, values, out);
  } else {
    hipFuncSetAttribute(reinterpret_cast<const void*>(traverse_kernel<false>),
                        hipFuncAttributeMaxDynamicSharedMemorySize, SH_BYTES);
    traverse_kernel<false><<<grid, NTHREADS, SH_BYTES, stream>>>(
        x, nullptr, thresholds, features, lefts, rights, values, out);
  }
}

// Round 5
// 87.362 us; speedup vs baseline: 2.6162x; 1.4116x over previous
//
#include <hip/hip_runtime.h>
#include <stdint.h>

#define BATCH     10000
#define NUM_TREES 1000
#define NUM_NODES 511
#define NFEAT     256
#define DEPTH     8
#define FLAT_NODES (NUM_TREES * NUM_NODES)

// ---------------- unrolled-tree layout in d_ws ----------------
// Tree unrolled into implicit depth-8 binary tree: position p (0..254
// internal) holds record {f32 thr, u32 feat}; children are 2p+1 / 2p+2.
// Leaf positions 255..510 contribute only vleaf[p-255] (f32).
#define TREE_BYTES 2040                          // 255 records * 8 B
#define VLEAF_OFF  ((size_t)NUM_TREES * TREE_BYTES)      // 2,040,000 (16-aligned)
#define WS_NEEDED  (VLEAF_OFF + (size_t)NUM_TREES * 256 * 4)

// ---------------- traverse geometry ----------------
#define BT 64            // batch rows per block
#define TT 48            // trees per block, single round
#define NTHREADS 1024
#define ILP 3            // trees per wave (16 waves * 3 = 48)
#define XS_BYTES  (NFEAT * 64 * 4)               // 65536, [feat][64] swizzled
#define NS_BYTES  (TT * TREE_BYTES)              // 97920
#define SH_BYTES  (XS_BYTES + NS_BYTES)          // 163456 <= 160 KiB
#define NCHUNK    (NS_BYTES / 8)                 // 12240 uint2 chunks
#define PREF      ((NCHUNK + NTHREADS - 1) / NTHREADS)   // 12
#define OUT_LD    (TT + 1)                       // 49 (odd -> conflict-free)

// ================= prepack: BFS-unroll each tree =================
// One wave per tree; n_s holds the node-id at each implicit position.
__global__ __launch_bounds__(256)
void unroll_kernel(const float* __restrict__ thr,
                   const int* __restrict__ feats,
                   const int* __restrict__ lefts,
                   const int* __restrict__ rights,
                   const float* __restrict__ values,
                   unsigned char* __restrict__ ws) {
  __shared__ uint16_t n_s[4][512];
  const int wv = threadIdx.x >> 6, lane = threadIdx.x & 63;
  const int tree = blockIdx.x * 4 + wv;          // grid=250 -> always < 1000
  const int base = tree * NUM_NODES;
  uint16_t* n = n_s[wv];
  uint2* rec   = (uint2*)(ws + (size_t)tree * TREE_BYTES);
  float* vleaf = (float*)(ws + VLEAF_OFF + (size_t)tree * 1024);

  if (lane == 0) n[0] = 0;
  __syncthreads();
  #pragma unroll
  for (int d = 0; d < 8; ++d) {
    const int lvl = (1 << d) - 1, cnt = 1 << d;
    for (int i = lane; i < cnt; i += 64) {
      int p  = lvl + i;
      int np = n[p];
      int nl = lefts[base + np], nr = rights[base + np];
      n[2 * p + 1] = (uint16_t)nl;
      n[2 * p + 2] = (uint16_t)nr;
      rec[p] = make_uint2(__float_as_uint(thr[base + np]),
                          (uint32_t)feats[base + np]);
    }
    __syncthreads();
  }
  // leaf values: positions 255..510
  #pragma unroll
  for (int i = lane; i < 256; i += 64)
    vleaf[i] = values[base + n[255 + i]];
}

// ================= main traversal =================
__global__ __launch_bounds__(NTHREADS, 1)
void traverse48(const float* __restrict__ x,
                const unsigned char* __restrict__ ws,
                float* __restrict__ out) {
  extern __shared__ unsigned char smem[];
  float* x_s = (float*)smem;                     // [256][64] swizzled
  unsigned char* nodes = smem + XS_BYTES;        // 48 trees * 2040 B
  float* out_s = (float*)nodes;                  // aliased after traversal

  const int tid  = threadIdx.x;
  const int wid  = tid >> 6;
  const int lane = tid & 63;
  const int b0   = blockIdx.y * BT;
  const int t0   = blockIdx.x * TT;

  // ---- issue x loads (4 float4/thread) ----
  const float4* xg = (const float4*)x;
  float4 xv[4];
  #pragma unroll
  for (int p = 0; p < 4; ++p) {
    int i = tid + p * NTHREADS;
    int row = i >> 6, c = i & 63;
    int gb = b0 + row;
    xv[p] = (gb < BATCH) ? xg[gb * 64 + c] : make_float4(0.f, 0.f, 0.f, 0.f);
  }
  // ---- issue node-region loads (linear 95.6 KB copy; garbage past tree
  //      1000 is safe: p stays bounded, feat masked to 8 bits) ----
  const uint2* src = (const uint2*)(ws + (size_t)t0 * TREE_BYTES);
  uint2 pf[PREF];
  #pragma unroll
  for (int k = 0; k < PREF; ++k) {
    int fi = tid + k * NTHREADS;
    pf[k] = (fi < NCHUNK) ? src[fi] : make_uint2(0u, 0u);
  }
  // ---- write x transposed+swizzled: bank = (row ^ ((feat>>2)&31)) ----
  #pragma unroll
  for (int p = 0; p < 4; ++p) {
    int i = tid + p * NTHREADS;
    int row = i >> 6, c = i & 63;
    int o = (c << 8) + (row ^ (c & 31));
    x_s[o]       = xv[p].x;
    x_s[o + 64]  = xv[p].y;
    x_s[o + 128] = xv[p].z;
    x_s[o + 192] = xv[p].w;
  }
  // ---- write nodes ----
  uint2* nd = (uint2*)nodes;
  #pragma unroll
  for (int k = 0; k < PREF; ++k) {
    int fi = tid + k * NTHREADS;
    if (fi < NCHUNK) nd[fi] = pf[k];
  }
  __syncthreads();

  // ---- traverse: wave wid owns trees t0+3*wid .. +2; lane = batch row ----
  const int lt = 3 * wid;
  const unsigned char* nb0 = nodes + (size_t)(lt + 0) * TREE_BYTES;
  const unsigned char* nb1 = nodes + (size_t)(lt + 1) * TREE_BYTES;
  const unsigned char* nb2 = nodes + (size_t)(lt + 2) * TREE_BYTES;
  int p0 = 0, p1 = 0, p2 = 0;
  #pragma unroll
  for (int d = 0; d < DEPTH; ++d) {
    uint2 r0 = *(const uint2*)(nb0 + p0 * 8);
    uint2 r1 = *(const uint2*)(nb1 + p1 * 8);
    uint2 r2 = *(const uint2*)(nb2 + p2 * 8);
    int f0 = r0.y & 255, f1 = r1.y & 255, f2 = r2.y & 255;
    float x0 = x_s[(f0 << 6) + (lane ^ ((f0 >> 2) & 31))];
    float x1 = x_s[(f1 << 6) + (lane ^ ((f1 >> 2) & 31))];
    float x2 = x_s[(f2 << 6) + (lane ^ ((f2 >> 2) & 31))];
    p0 = 2 * p0 + 1 + (x0 >= __uint_as_float(r0.x));
    p1 = 2 * p1 + 1 + (x1 >= __uint_as_float(r1.x));
    p2 = 2 * p2 + 1 + (x2 >= __uint_as_float(r2.x));
  }
  // leaf values from prepacked global table (L2/L3-resident, 1 MB)
  const float* vl = (const float*)(ws + VLEAF_OFF);
  int g0 = t0 + lt, g1 = g0 + 1, g2 = g0 + 2;
  int c0 = (g0 < NUM_TREES ? g0 : 0);
  int c1 = (g1 < NUM_TREES ? g1 : 0);
  int c2 = (g2 < NUM_TREES ? g2 : 0);
  float v0 = vl[(size_t)c0 * 256 + (p0 - 255)];
  float v1 = vl[(size_t)c1 * 256 + (p1 - 255)];
  float v2 = vl[(size_t)c2 * 256 + (p2 - 255)];

  __syncthreads();                     // all node reads done -> alias as out_s
  out_s[lane * OUT_LD + lt + 0] = v0;
  out_s[lane * OUT_LD + lt + 1] = v1;
  out_s[lane * OUT_LD + lt + 2] = v2;
  __syncthreads();

  // ---- flush 64x48 tile, coalesced 64 B chunks ----
  #pragma unroll
  for (int k = 0; k < 3; ++k) {
    int row = tid >> 4, col = (tid & 15) + 16 * k;
    int gb = b0 + row, gt = t0 + col;
    if (gb < BATCH && gt < NUM_TREES)
      out[(size_t)gb * NUM_TREES + gt] = out_s[row * OUT_LD + col];
  }
}

// ================= fallback (R4 kernel, no-ws path) =================
#define FB_BT 64
#define FB_TT 64
#define FB_TPR 16
#define FB_NROUNDS 4
#define FB_NTHREADS 1024
#define FB_XS (NFEAT * 64 * 4)
#define FB_NSU (FB_TPR * NUM_NODES)
#define FB_NS (FB_NSU * 8)
#define FB_OLD (FB_TT + 1)
#define FB_OS (FB_BT * FB_OLD * 4)
#define FB_SH (FB_XS + FB_NS + FB_OS)
#define FB_PREF ((FB_NSU + FB_NTHREADS - 1) / FB_NTHREADS)

__global__ __launch_bounds__(FB_NTHREADS, 1)
void fb_traverse(const float* __restrict__ x,
                 const float* __restrict__ thrg,
                 const int* __restrict__ featg,
                 const int* __restrict__ leftg,
                 const int* __restrict__ rightg,
                 const float* __restrict__ values,
                 float* __restrict__ out) {
  extern __shared__ unsigned char smem[];
  float* x_s     = (float*)smem;
  uint2* nodes_s = (uint2*)(smem + FB_XS);
  float* out_s   = (float*)(smem + FB_XS + FB_NS);
  const int tid = threadIdx.x, wid = tid >> 6, lane = tid & 63;
  const int b0 = blockIdx.y * FB_BT, t0 = blockIdx.x * FB_TT;
  uint2 pf[FB_PREF];
  auto load_round = [&](int rr) {
    const int gbase = (t0 + rr * FB_TPR) * NUM_NODES;
    #pragma unroll
    for (int k = 0; k < FB_PREF; ++k) {
      int fi = tid + k * FB_NTHREADS;
      uint2 v = make_uint2(0u, 0u);
      if (fi < FB_NSU) {
        int gi = gbase + fi;
        if (gi < FLAT_NODES) {
          uint32_t meta = (uint32_t)featg[gi] | ((uint32_t)leftg[gi] << 8) |
                          ((uint32_t)rightg[gi] << 20);
          v = make_uint2(__float_as_uint(thrg[gi]), meta);
        }
      }
      pf[k] = v;
    }
  };
  auto write_nodes = [&]() {
    #pragma unroll
    for (int k = 0; k < FB_PREF; ++k) {
      int fi = tid + k * FB_NTHREADS;
      if (fi < FB_NSU) nodes_s[fi] = pf[k];
    }
  };
  load_round(0);
  {
    const float4* xg = (const float4*)x;
    #pragma unroll
    for (int p = 0; p < (FB_BT * (NFEAT / 4)) / FB_NTHREADS; ++p) {
      int i = tid + p * FB_NTHREADS;
      int row = i >> 6, c = i & 63;
      int gb = b0 + row;
      float4 v = make_float4(0.f, 0.f, 0.f, 0.f);
      if (gb < BATCH) v = xg[gb * (NFEAT / 4) + c];
      int o = (c << 8) + (row ^ (c & 31));
      x_s[o] = v.x; x_s[o + 64] = v.y; x_s[o + 128] = v.z; x_s[o + 192] = v.w;
    }
  }
  write_nodes();
  __syncthreads();
  for (int r = 0; r < FB_NROUNDS; ++r) {
    if (r + 1 < FB_NROUNDS) load_round(r + 1);
    const uint2* nA = nodes_s + wid * NUM_NODES;
    const int tr0 = t0 + r * FB_TPR;
    const int gta = tr0 + wid;
    const int offA = (gta < NUM_TREES ? gta : 0) * NUM_NODES;
    uint2 na = nA[0];
    float va = 0.f;
    #pragma unroll
    for (int d = 0; d < DEPTH; ++d) {
      int fa = na.y & 0xFF;
      int la = (na.y >> 8) & 0xFFF;
      int ra = (int)(na.y >> 20);
      float xa = x_s[(fa << 6) + (lane ^ ((fa >> 2) & 31))];
      if (d < DEPTH - 1) {
        uint2 nla = nA[la], nra = nA[ra];
        na = (xa >= __uint_as_float(na.x)) ? nra : nla;
      } else {
        float vla = values[offA + la], vra = values[offA + ra];
        va = (xa >= __uint_as_float(na.x)) ? vra : vla;
      }
    }
    out_s[lane * FB_OLD + r * FB_TPR + wid] = va;
    __syncthreads();
    if (r + 1 < FB_NROUNDS) { write_nodes(); __syncthreads(); }
  }
  {
    const int gt = t0 + lane;
    #pragma unroll
    for (int p = 0; p < FB_BT / 16; ++p) {
      int row = p * 16 + wid;
      int gb = b0 + row;
      if (gb < BATCH && gt < NUM_TREES)
        out[gb * NUM_TREES + gt] = out_s[row * FB_OLD + lane];
    }
  }
}

extern "C" void kernel_launch(void* const* d_in, const int* in_sizes, int n_in,
                              void* d_out, int out_size, void* d_ws, size_t ws_size,
                              hipStream_t stream) {
  const float* x          = (const float*)d_in[0];
  const float* thresholds = (const float*)d_in[1];
  const float* values     = (const float*)d_in[2];
  const int*   lefts      = (const int*)d_in[3];
  const int*   rights     = (const int*)d_in[4];
  const int*   features   = (const int*)d_in[5];
  float* out = (float*)d_out;

  if (ws_size >= WS_NEEDED) {
    unsigned char* ws = (unsigned char*)d_ws;
    unroll_kernel<<<NUM_TREES / 4, 256, 0, stream>>>(
        thresholds, features, lefts, rights, values, ws);
    hipFuncSetAttribute(reinterpret_cast<const void*>(traverse48),
                        hipFuncAttributeMaxDynamicSharedMemorySize, SH_BYTES);
    dim3 grid((NUM_TREES + TT - 1) / TT, (BATCH + BT - 1) / BT);   // 21 x 157
    traverse48<<<grid, NTHREADS, SH_BYTES, stream>>>(x, ws, out);
  } else {
    hipFuncSetAttribute(reinterpret_cast<const void*>(fb_traverse),
                        hipFuncAttributeMaxDynamicSharedMemorySize, FB_SH);
    dim3 grid((NUM_TREES + FB_TT - 1) / FB_TT, (BATCH + FB_BT - 1) / FB_BT);
    fb_traverse<<<grid, FB_NTHREADS, FB_SH, stream>>>(
        x, thresholds, features, lefts, rights, values, out);
  }
}

// Round 6
// 71.724 us; speedup vs baseline: 3.1866x; 1.2180x over previous
//
#include <hip/hip_runtime.h>
#include <stdint.h>

#define BATCH     10000
#define NUM_TREES 1000
#define NUM_NODES 511
#define NFEAT     256
#define DEPTH     8
#define FLAT_NODES (NUM_TREES * NUM_NODES)

// ---------------- 2-level fused record layout in d_ws ----------------
// Implicit depth-8 tree. Records exist at even depths {0,2,4,6}:
//   rec = {f32 thr_p, f32 thr_l, f32 thr_r, u32 f_p|f_l<<8|f_r<<16}
// rec index = EBASE[d/2] + local, EBASE = {0,1,5,21}; 85 recs = 1360 B/tree.
// One b128 read + 2 compares descends 2 levels: local' = 4*local + 2c0 + c1.
// Leaf (depth 8): vleaf[local] per tree (256 f32 = 1024 B).
#define TREE_BYTES 1360
#define VLEAF_OFF  ((size_t)NUM_TREES * TREE_BYTES)          // 1,360,000
#define WS_NEEDED  (VLEAF_OFF + (size_t)NUM_TREES * 256 * 4) // 2,384,000

// ---------------- traverse geometry ----------------
#define BT 64            // batch rows per block
#define TT 64            // trees per block, single round
#define NTHREADS 1024    // 16 waves
#define ILP 4            // trees per wave
#define XS_BYTES  (NFEAT * 64 * 4)               // 65536, [feat][64] swizzled
#define NS_BYTES  (TT * TREE_BYTES)              // 87040
#define SH_BYTES  (XS_BYTES + NS_BYTES)          // 152576 <= 160 KiB
#define NCHUNK    (NS_BYTES / 16)                // 5440 uint4 chunks
#define PREF      ((NCHUNK + NTHREADS - 1) / NTHREADS)   // 6
#define OUT_LD    (TT + 1)                       // 65

// ================= prepack: BFS-unroll into 2-level records =================
__global__ __launch_bounds__(256)
void unroll_kernel(const float* __restrict__ thr,
                   const int* __restrict__ feats,
                   const int* __restrict__ lefts,
                   const int* __restrict__ rights,
                   const float* __restrict__ values,
                   unsigned char* __restrict__ ws) {
  __shared__ uint16_t n_s[4][512];
  const int wv = threadIdx.x >> 6, lane = threadIdx.x & 63;
  const int tree = blockIdx.x * 4 + wv;          // grid=250 -> always < 1000
  const int base = tree * NUM_NODES;
  uint16_t* n = n_s[wv];
  uint4* rec   = (uint4*)(ws + (size_t)tree * TREE_BYTES);
  float* vleaf = (float*)(ws + VLEAF_OFF + (size_t)tree * 1024);

  if (lane == 0) n[0] = 0;
  __syncthreads();
  const int EBASE[4] = {0, 1, 5, 21};
  #pragma unroll
  for (int d = 0; d < 8; ++d) {
    const int lvl = (1 << d) - 1, cnt = 1 << d;
    for (int i = lane; i < cnt; i += 64) {
      int p  = lvl + i;
      int np = n[p];
      int nl = lefts[base + np], nr = rights[base + np];
      n[2 * p + 1] = (uint16_t)nl;
      n[2 * p + 2] = (uint16_t)nr;
      if ((d & 1) == 0) {
        uint32_t f3 = (uint32_t)feats[base + np] |
                      ((uint32_t)feats[base + nl] << 8) |
                      ((uint32_t)feats[base + nr] << 16);
        rec[EBASE[d >> 1] + i] =
            make_uint4(__float_as_uint(thr[base + np]),
                       __float_as_uint(thr[base + nl]),
                       __float_as_uint(thr[base + nr]), f3);
      }
    }
    __syncthreads();
  }
  #pragma unroll
  for (int i = lane; i < 256; i += 64)
    vleaf[i] = values[base + n[255 + i]];
}

// ================= main traversal =================
__global__ __launch_bounds__(NTHREADS, 1)
void traverse64(const float* __restrict__ x,
                const unsigned char* __restrict__ ws,
                float* __restrict__ out) {
  extern __shared__ unsigned char smem[];
  float* x_s = (float*)smem;                     // [256][64] swizzled
  unsigned char* nodes = smem + XS_BYTES;        // 64 trees * 1360 B
  float* out_s = (float*)nodes;                  // aliased after traversal

  const int tid  = threadIdx.x;
  const int wid  = tid >> 6;
  const int lane = tid & 63;
  const int b0   = blockIdx.y * BT;
  const int t0   = blockIdx.x * TT;

  // ---- issue x loads (4 float4/thread) ----
  const float4* xg = (const float4*)x;
  float4 xv[4];
  #pragma unroll
  for (int p = 0; p < 4; ++p) {
    int i = tid + p * NTHREADS;
    int row = i >> 6, c = i & 63;
    int gb = b0 + row;
    xv[p] = (gb < BATCH) ? xg[gb * 64 + c] : make_float4(0.f, 0.f, 0.f, 0.f);
  }
  // ---- issue node-region loads (linear 85 KB; garbage past tree 1000 is
  //      safe: local stays bounded by construction, feats masked) ----
  const uint4* src = (const uint4*)(ws + (size_t)t0 * TREE_BYTES);
  uint4 pf[PREF];
  #pragma unroll
  for (int k = 0; k < PREF; ++k) {
    int fi = tid + k * NTHREADS;
    pf[k] = (fi < NCHUNK) ? src[fi] : make_uint4(0u, 0u, 0u, 0u);
  }
  // ---- write x transposed+swizzled: bank = lane ^ ((feat>>2)&31) ----
  #pragma unroll
  for (int p = 0; p < 4; ++p) {
    int i = tid + p * NTHREADS;
    int row = i >> 6, c = i & 63;
    int o = (c << 8) + (row ^ (c & 31));
    x_s[o]       = xv[p].x;
    x_s[o + 64]  = xv[p].y;
    x_s[o + 128] = xv[p].z;
    x_s[o + 192] = xv[p].w;
  }
  // ---- write nodes (b128) ----
  uint4* nd = (uint4*)nodes;
  #pragma unroll
  for (int k = 0; k < PREF; ++k) {
    int fi = tid + k * NTHREADS;
    if (fi < NCHUNK) nd[fi] = pf[k];
  }
  __syncthreads();

  // ---- traverse: wave wid owns trees t0+4*wid..+3; lane = batch row ----
  const unsigned char* nb = nodes + (size_t)(4 * wid) * TREE_BYTES;
  int loc[ILP] = {0, 0, 0, 0};
  #pragma unroll
  for (int it = 0; it < 4; ++it) {
    const int eoff = (it == 0) ? 0 : (it == 1) ? 16 : (it == 2) ? 80 : 336;
    uint4 r[ILP];
    #pragma unroll
    for (int c = 0; c < ILP; ++c)
      r[c] = *(const uint4*)(nb + c * TREE_BYTES + loc[c] * 16 + eoff);
    float xp[ILP], xl[ILP], xr[ILP];
    #pragma unroll
    for (int c = 0; c < ILP; ++c) {
      int fp = r[c].w & 255, fl = (r[c].w >> 8) & 255, fr = (r[c].w >> 16) & 255;
      xp[c] = x_s[(fp << 6) + (lane ^ ((fp >> 2) & 31))];
      xl[c] = x_s[(fl << 6) + (lane ^ ((fl >> 2) & 31))];
      xr[c] = x_s[(fr << 6) + (lane ^ ((fr >> 2) & 31))];
    }
    #pragma unroll
    for (int c = 0; c < ILP; ++c) {
      bool c0  = (xp[c] >= __uint_as_float(r[c].x));
      float xc = c0 ? xr[c] : xl[c];
      float tc = __uint_as_float(c0 ? r[c].z : r[c].y);
      bool c1  = (xc >= tc);
      loc[c] = 4 * loc[c] + 2 * (int)c0 + (int)c1;
    }
  }
  // ---- leaf values from prepacked table (L2-resident, 1 MB) ----
  const float* vl = (const float*)(ws + VLEAF_OFF);
  float v[ILP];
  #pragma unroll
  for (int c = 0; c < ILP; ++c) {
    int g  = t0 + 4 * wid + c;
    int cg = (g < NUM_TREES) ? g : 0;
    v[c] = vl[(size_t)cg * 256 + loc[c]];
  }

  __syncthreads();                     // all node reads done -> alias as out_s
  #pragma unroll
  for (int c = 0; c < ILP; ++c)
    out_s[lane * OUT_LD + 4 * wid + c] = v[c];
  __syncthreads();

  // ---- flush 64x64 tile, coalesced 64 B chunks ----
  #pragma unroll
  for (int k = 0; k < 4; ++k) {
    int row = tid >> 4, col = (tid & 15) + 16 * k;
    int gb = b0 + row, gt = t0 + col;
    if (gb < BATCH && gt < NUM_TREES)
      out[(size_t)gb * NUM_TREES + gt] = out_s[row * OUT_LD + col];
  }
}

// ================= fallback (no-ws path) =================
#define FB_BT 64
#define FB_TT 64
#define FB_TPR 16
#define FB_NROUNDS 4
#define FB_NTHREADS 1024
#define FB_XS (NFEAT * 64 * 4)
#define FB_NSU (FB_TPR * NUM_NODES)
#define FB_NS (FB_NSU * 8)
#define FB_OLD (FB_TT + 1)
#define FB_OS (FB_BT * FB_OLD * 4)
#define FB_SH (FB_XS + FB_NS + FB_OS)
#define FB_PREF ((FB_NSU + FB_NTHREADS - 1) / FB_NTHREADS)

__global__ __launch_bounds__(FB_NTHREADS, 1)
void fb_traverse(const float* __restrict__ x,
                 const float* __restrict__ thrg,
                 const int* __restrict__ featg,
                 const int* __restrict__ leftg,
                 const int* __restrict__ rightg,
                 const float* __restrict__ values,
                 float* __restrict__ out) {
  extern __shared__ unsigned char smem[];
  float* x_s     = (float*)smem;
  uint2* nodes_s = (uint2*)(smem + FB_XS);
  float* out_s   = (float*)(smem + FB_XS + FB_NS);
  const int tid = threadIdx.x, wid = tid >> 6, lane = tid & 63;
  const int b0 = blockIdx.y * FB_BT, t0 = blockIdx.x * FB_TT;
  uint2 pf[FB_PREF];
  auto load_round = [&](int rr) {
    const int gbase = (t0 + rr * FB_TPR) * NUM_NODES;
    #pragma unroll
    for (int k = 0; k < FB_PREF; ++k) {
      int fi = tid + k * FB_NTHREADS;
      uint2 v = make_uint2(0u, 0u);
      if (fi < FB_NSU) {
        int gi = gbase + fi;
        if (gi < FLAT_NODES) {
          uint32_t meta = (uint32_t)featg[gi] | ((uint32_t)leftg[gi] << 8) |
                          ((uint32_t)rightg[gi] << 20);
          v = make_uint2(__float_as_uint(thrg[gi]), meta);
        }
      }
      pf[k] = v;
    }
  };
  auto write_nodes = [&]() {
    #pragma unroll
    for (int k = 0; k < FB_PREF; ++k) {
      int fi = tid + k * FB_NTHREADS;
      if (fi < FB_NSU) nodes_s[fi] = pf[k];
    }
  };
  load_round(0);
  {
    const float4* xg = (const float4*)x;
    #pragma unroll
    for (int p = 0; p < (FB_BT * (NFEAT / 4)) / FB_NTHREADS; ++p) {
      int i = tid + p * FB_NTHREADS;
      int row = i >> 6, c = i & 63;
      int gb = b0 + row;
      float4 v = make_float4(0.f, 0.f, 0.f, 0.f);
      if (gb < BATCH) v = xg[gb * (NFEAT / 4) + c];
      int o = (c << 8) + (row ^ (c & 31));
      x_s[o] = v.x; x_s[o + 64] = v.y; x_s[o + 128] = v.z; x_s[o + 192] = v.w;
    }
  }
  write_nodes();
  __syncthreads();
  for (int r = 0; r < FB_NROUNDS; ++r) {
    if (r + 1 < FB_NROUNDS) load_round(r + 1);
    const uint2* nA = nodes_s + wid * NUM_NODES;
    const int tr0 = t0 + r * FB_TPR;
    const int gta = tr0 + wid;
    const int offA = (gta < NUM_TREES ? gta : 0) * NUM_NODES;
    uint2 na = nA[0];
    float va = 0.f;
    #pragma unroll
    for (int d = 0; d < DEPTH; ++d) {
      int fa = na.y & 0xFF;
      int la = (na.y >> 8) & 0xFFF;
      int ra = (int)(na.y >> 20);
      float xa = x_s[(fa << 6) + (lane ^ ((fa >> 2) & 31))];
      if (d < DEPTH - 1) {
        uint2 nla = nA[la], nra = nA[ra];
        na = (xa >= __uint_as_float(na.x)) ? nra : nla;
      } else {
        float vla = values[offA + la], vra = values[offA + ra];
        va = (xa >= __uint_as_float(na.x)) ? vra : vla;
      }
    }
    out_s[lane * FB_OLD + r * FB_TPR + wid] = va;
    __syncthreads();
    if (r + 1 < FB_NROUNDS) { write_nodes(); __syncthreads(); }
  }
  {
    const int gt = t0 + lane;
    #pragma unroll
    for (int p = 0; p < FB_BT / 16; ++p) {
      int row = p * 16 + wid;
      int gb = b0 + row;
      if (gb < BATCH && gt < NUM_TREES)
        out[gb * NUM_TREES + gt] = out_s[row * FB_OLD + lane];
    }
  }
}

extern "C" void kernel_launch(void* const* d_in, const int* in_sizes, int n_in,
                              void* d_out, int out_size, void* d_ws, size_t ws_size,
                              hipStream_t stream) {
  const float* x          = (const float*)d_in[0];
  const float* thresholds = (const float*)d_in[1];
  const float* values     = (const float*)d_in[2];
  const int*   lefts      = (const int*)d_in[3];
  const int*   rights     = (const int*)d_in[4];
  const int*   features   = (const int*)d_in[5];
  float* out = (float*)d_out;

  if (ws_size >= WS_NEEDED) {
    unsigned char* ws = (unsigned char*)d_ws;
    unroll_kernel<<<NUM_TREES / 4, 256, 0, stream>>>(
        thresholds, features, lefts, rights, values, ws);
    hipFuncSetAttribute(reinterpret_cast<const void*>(traverse64),
                        hipFuncAttributeMaxDynamicSharedMemorySize, SH_BYTES);
    dim3 grid((NUM_TREES + TT - 1) / TT, (BATCH + BT - 1) / BT);   // 16 x 157
    traverse64<<<grid, NTHREADS, SH_BYTES, stream>>>(x, ws, out);
  } else {
    hipFuncSetAttribute(reinterpret_cast<const void*>(fb_traverse),
                        hipFuncAttributeMaxDynamicSharedMemorySize, FB_SH);
    dim3 grid((NUM_TREES + FB_TT - 1) / FB_TT, (BATCH + FB_BT - 1) / FB_BT);
    fb_traverse<<<grid, FB_NTHREADS, FB_SH, stream>>>(
        x, thresholds, features, lefts, rights, values, out);
  }
}